// Round 3
// baseline (659.653 us; speedup 1.0000x reference)
//
#include <hip/hip_runtime.h>
#include <hip/hip_bf16.h>

#define D_MODEL 1024
#define F_DIM   2048
#define NE      8
#define NTOK    8192
#define MAXT    72
#define HBLK    32          // histogram/scatter blocks (256 tokens each)

typedef __attribute__((ext_vector_type(8))) short bf16x8;
typedef __attribute__((ext_vector_type(4))) float f32x4;

__device__ __forceinline__ unsigned short f2b(float f) {
    unsigned int u = __float_as_uint(f);
    u += 0x7FFFu + ((u >> 16) & 1u);          // RNE
    return (unsigned short)(u >> 16);
}
__device__ __forceinline__ unsigned int pack2(float a, float b) {
    return (unsigned int)f2b(a) | ((unsigned int)f2b(b) << 16);
}
__device__ __forceinline__ void async16(const void* g, void* l) {
    __builtin_amdgcn_global_load_lds((const __attribute__((address_space(1))) void*)g,
                                     (__attribute__((address_space(3))) void*)l, 16, 0, 0);
}

// ------------- ternary quantization: fp32 rows -> bf16 {-s,0,+s} ----------------
template <int K>
__global__ __launch_bounds__(256) void quant_rows(const float* __restrict__ W,
                                                  unsigned short* __restrict__ Q) {
    constexpr int PER = K / 256;
    constexpr int PV  = PER / 4;
    __shared__ float sred[4];
    const int tid = threadIdx.x;
    const size_t row = blockIdx.x;
    const float4* Wv = (const float4*)(W + row * (size_t)K) + tid * PV;
    float4 v[PV];
#pragma unroll
    for (int i = 0; i < PV; i++) v[i] = Wv[i];
    float s = 0.f;
#pragma unroll
    for (int i = 0; i < PV; i++)
        s += fabsf(v[i].x) + fabsf(v[i].y) + fabsf(v[i].z) + fabsf(v[i].w);
#pragma unroll
    for (int o = 32; o > 0; o >>= 1) s += __shfl_down(s, o);
    if ((tid & 63) == 0) sred[tid >> 6] = s;
    __syncthreads();
    float scale = (sred[0] + sred[1] + sred[2] + sred[3]) * (1.0f / K);
    scale = fmaxf(scale, 1e-5f);
    const float inv = 1.0f / scale;
    unsigned int* Qu = (unsigned int*)(Q + row * (size_t)K) + tid * (PER / 2);
#pragma unroll
    for (int i = 0; i < PV; i++) {
        float q0 = fminf(1.f, fmaxf(-1.f, rintf(v[i].x * inv))) * scale;
        float q1 = fminf(1.f, fmaxf(-1.f, rintf(v[i].y * inv))) * scale;
        float q2 = fminf(1.f, fmaxf(-1.f, rintf(v[i].z * inv))) * scale;
        float q3 = fminf(1.f, fmaxf(-1.f, rintf(v[i].w * inv))) * scale;
        Qu[2 * i]     = pack2(q0, q1);
        Qu[2 * i + 1] = pack2(q2, q3);
    }
}

// -------- fused LayerNorm + router: ONE WAVE PER TOKEN, no atomics --------------
__global__ __launch_bounds__(256) void ln_router(const float* __restrict__ x,
                                                 const float* __restrict__ gamma,
                                                 const float* __restrict__ beta,
                                                 const float* __restrict__ rw,
                                                 unsigned short* __restrict__ h,
                                                 int* __restrict__ top_idx,
                                                 float* __restrict__ top_prob) {
    const int lane = threadIdx.x & 63;
    const size_t tok = blockIdx.x * 4 + (threadIdx.x >> 6);

    const float4* xr = (const float4*)(x + tok * D_MODEL);
    float4 xv[4];
#pragma unroll
    for (int i = 0; i < 4; i++) xv[i] = xr[lane + 64 * i];
    float s = 0.f, q = 0.f;
#pragma unroll
    for (int i = 0; i < 4; i++) {
        s += xv[i].x + xv[i].y + xv[i].z + xv[i].w;
        q += xv[i].x * xv[i].x + xv[i].y * xv[i].y + xv[i].z * xv[i].z + xv[i].w * xv[i].w;
    }
#pragma unroll
    for (int o = 32; o > 0; o >>= 1) { s += __shfl_down(s, o); q += __shfl_down(q, o); }
    s = __shfl(s, 0); q = __shfl(q, 0);
    const float mean = s * (1.0f / D_MODEL);
    const float rstd = rsqrtf(q * (1.0f / D_MODEL) - mean * mean + 1e-5f);

    float4 hv[4];
    unsigned int* hr = (unsigned int*)(h + tok * D_MODEL);
#pragma unroll
    for (int i = 0; i < 4; i++) {
        const float4 g  = ((const float4*)gamma)[lane + 64 * i];
        const float4 bt = ((const float4*)beta)[lane + 64 * i];
        hv[i].x = (xv[i].x - mean) * rstd * g.x + bt.x;
        hv[i].y = (xv[i].y - mean) * rstd * g.y + bt.y;
        hv[i].z = (xv[i].z - mean) * rstd * g.z + bt.z;
        hv[i].w = (xv[i].w - mean) * rstd * g.w + bt.w;
        hr[2 * (lane + 64 * i)]     = pack2(hv[i].x, hv[i].y);
        hr[2 * (lane + 64 * i) + 1] = pack2(hv[i].z, hv[i].w);
    }

    float acc[NE];
#pragma unroll
    for (int e = 0; e < NE; e++) {
        const float4* rr = (const float4*)(rw + e * D_MODEL);
        float a = 0.f;
#pragma unroll
        for (int i = 0; i < 4; i++) {
            const float4 r = rr[lane + 64 * i];
            a += hv[i].x * r.x + hv[i].y * r.y + hv[i].z * r.z + hv[i].w * r.w;
        }
        acc[e] = a;
    }
#pragma unroll
    for (int e = 0; e < NE; e++) {
#pragma unroll
        for (int o = 32; o > 0; o >>= 1) acc[e] += __shfl_down(acc[e], o);
    }
    if (lane == 0) {
        float m = acc[0]; int bi = 0;
#pragma unroll
        for (int e = 1; e < NE; e++) { if (acc[e] > m) { m = acc[e]; bi = e; } }
        float se = 0.f;
#pragma unroll
        for (int e = 0; e < NE; e++) se += __expf(acc[e] - m);
        top_idx[tok]  = bi;
        top_prob[tok] = 1.0f / se;
    }
}

// ------- routing plan: per-block LDS histogram -> scan -> LDS-cursor scatter -----
__global__ __launch_bounds__(256) void hist_kernel(const int* __restrict__ top_idx,
                                                   int* __restrict__ blockhist) {
    __shared__ int lh[NE];
    if (threadIdx.x < NE) lh[threadIdx.x] = 0;
    __syncthreads();
    const int t = blockIdx.x * 256 + threadIdx.x;
    atomicAdd(&lh[top_idx[t]], 1);
    __syncthreads();
    if (threadIdx.x < NE) blockhist[blockIdx.x * NE + threadIdx.x] = lh[threadIdx.x];
}

__global__ void scan_plan(const int* __restrict__ blockhist, int* __restrict__ base,
                          int4* __restrict__ tilemap, int* __restrict__ tok_perm) {
    if (threadIdx.x != 0) return;
    int counts[NE];
#pragma unroll
    for (int e = 0; e < NE; e++) counts[e] = 0;
    for (int b = 0; b < HBLK; b++)
        for (int e = 0; e < NE; e++) counts[e] += blockhist[b * NE + e];
    int off = 0, slot = 0;
    int offsets[NE];
    for (int e = 0; e < NE; e++) {
        offsets[e] = off;
        for (int k = 0; k < counts[e]; k += 128) {
            int4 t; t.x = e; t.y = off + k; t.z = min(128, counts[e] - k); t.w = 0;
            tilemap[slot++] = t;
        }
        off += counts[e];
    }
    for (; slot < MAXT; slot++) { int4 t; t.x = 0; t.y = 0; t.z = 0; t.w = 0; tilemap[slot] = t; }
    for (int e = 0; e < NE; e++) {
        int r = offsets[e];
        for (int b = 0; b < HBLK; b++) { base[b * NE + e] = r; r += blockhist[b * NE + e]; }
    }
    for (int i = 0; i < 128; i++) tok_perm[NTOK + i] = 0;   // pad for gather-tile A loads
}

__global__ __launch_bounds__(256) void scatter_tokens(const int* __restrict__ top_idx,
                                                      const float* __restrict__ top_prob,
                                                      const int* __restrict__ base,
                                                      int* __restrict__ tok_perm,
                                                      float* __restrict__ probg) {
    __shared__ int cur[NE];
    if (threadIdx.x < NE) cur[threadIdx.x] = base[blockIdx.x * NE + threadIdx.x];
    __syncthreads();
    const int t = blockIdx.x * 256 + threadIdx.x;
    const int e = top_idx[t];
    const int pos = atomicAdd(&cur[e], 1);     // LDS atomic — block-local, cheap
    tok_perm[pos] = t;
    probg[pos] = top_prob[t];
}

// ---------------- m97-style bf16 NT GEMM: C[M,N] = A[M,K] * B[N,K]^T ------------
// A,B bf16; EPI: 0 silu->bf16 (shared G1), 1 fp32 store (shared G2),
//              2 tiled + A-gather via tok_perm, silu->bf16 (routed G1),
//              3 tiled scatter-add fp32 out[tok] += p*v (routed G2)
template <int EPI>
__global__ __launch_bounds__(256) void gemm_nt(const unsigned short* __restrict__ A,
                                               const unsigned short* __restrict__ Bw,
                                               void* __restrict__ Cv,
                                               int N, int K,
                                               const int4* __restrict__ tilemap,
                                               long long bstride,
                                               const int* __restrict__ tok_perm,
                                               const float* __restrict__ probg) {
    int m0, rowsValid;
    const unsigned short* B = Bw;
    if (EPI >= 2) {
        int4 tm = tilemap[blockIdx.y];
        rowsValid = tm.z;
        if (rowsValid == 0) return;
        m0 = tm.y;
        B += (size_t)tm.x * (size_t)bstride;
    } else {
        m0 = blockIdx.y * 128;
        rowsValid = 128;
    }
    const int n0 = blockIdx.x * 128;

    __shared__ unsigned short As[128 * 32];
    __shared__ unsigned short Bs[128 * 32];

    const int tid = threadIdx.x;
    const int lane = tid & 63;
    const int w = tid >> 6;
    const int wm = w >> 1, wn = w & 1;

    f32x4 acc[4][4];
#pragma unroll
    for (int i = 0; i < 4; i++)
#pragma unroll
        for (int j = 0; j < 4; j++) acc[i][j] = (f32x4){0.f, 0.f, 0.f, 0.f};

    const int rS = w * 16 + (lane >> 2);
    const int cS = (lane & 3) * 8;
    size_t ar0, ar1;
    if (EPI == 2) {                       // A-row gather through token permutation
        ar0 = (size_t)tok_perm[m0 + rS] * (size_t)K;
        ar1 = (size_t)tok_perm[m0 + rS + 64] * (size_t)K;
    } else {
        ar0 = (size_t)(m0 + rS) * (size_t)K;
        ar1 = (size_t)(m0 + rS + 64) * (size_t)K;
    }
    const unsigned short* a0 = A + ar0 + cS;
    const unsigned short* a1 = A + ar1 + cS;
    const unsigned short* b0 = B + (size_t)(n0 + rS) * K + cS;
    const unsigned short* b1 = B + (size_t)(n0 + rS + 64) * K + cS;
    unsigned short* asl = As + w * 512;
    unsigned short* bsl = Bs + w * 512;

    const int fr = lane & 15, fq = lane >> 4;
    const bf16x8* Ar = (const bf16x8*)As;
    const bf16x8* Br = (const bf16x8*)Bs;
    const int aBase = (wm * 64 + fr) * 4 + fq;
    const int bBase = (wn * 64 + fr) * 4 + fq;

    for (int k0 = 0; k0 < K; k0 += 32) {
        async16(a0 + k0, asl);
        async16(a1 + k0, asl + 2048);
        async16(b0 + k0, bsl);
        async16(b1 + k0, bsl + 2048);
        __syncthreads();
        bf16x8 af[4], bfr[4];
#pragma unroll
        for (int i = 0; i < 4; i++) af[i] = Ar[aBase + i * 64];
#pragma unroll
        for (int j = 0; j < 4; j++) bfr[j] = Br[bBase + j * 64];
#pragma unroll
        for (int i = 0; i < 4; i++)
#pragma unroll
            for (int j = 0; j < 4; j++)
                acc[i][j] = __builtin_amdgcn_mfma_f32_16x16x32_bf16(af[i], bfr[j], acc[i][j], 0, 0, 0);
        __syncthreads();
    }

    // epilogue: C/D layout col=lane&15, row=quad*4+reg (m89-verified)
#pragma unroll
    for (int i = 0; i < 4; i++) {
        const int rb = wm * 64 + i * 16 + fq * 4;
#pragma unroll
        for (int t = 0; t < 4; t++) {
            const int r = rb + t;
            if (r < rowsValid) {
#pragma unroll
                for (int j = 0; j < 4; j++) {
                    const int c = n0 + wn * 64 + j * 16 + fr;
                    float v = acc[i][j][t];
                    if (EPI == 0 || EPI == 2) {
                        v = v / (1.0f + __expf(-v));
                        ((unsigned short*)Cv)[(size_t)(m0 + r) * N + c] = f2b(v);
                    } else if (EPI == 1) {
                        ((float*)Cv)[(size_t)(m0 + r) * N + c] = v;
                    } else {
                        const int tokr = tok_perm[m0 + r];
                        const float p = probg[m0 + r];
                        float* crow = (float*)Cv + (size_t)tokr * N;
                        crow[c] = crow[c] + p * v;
                    }
                }
            }
        }
    }
}

// ---------------- launch ---------------------------------------------------------
extern "C" void kernel_launch(void* const* d_in, const int* in_sizes, int n_in,
                              void* d_out, int out_size, void* d_ws, size_t ws_size,
                              hipStream_t stream) {
    const float* x   = (const float*)d_in[0];
    const float* sw1 = (const float*)d_in[1];
    const float* sw2 = (const float*)d_in[2];
    const float* ew1 = (const float*)d_in[3];
    const float* ew2 = (const float*)d_in[4];
    const float* rw  = (const float*)d_in[5];
    const float* gam = (const float*)d_in[6];
    const float* bet = (const float*)d_in[7];
    float* out = (float*)d_out;

    char* ws = (char*)d_ws;
    const size_t H_OFF    = 0;
    const size_t SW1Q_OFF = H_OFF + (size_t)NTOK * D_MODEL * 2;
    const size_t SW2Q_OFF = SW1Q_OFF + (size_t)F_DIM * D_MODEL * 2;
    const size_t EW1Q_OFF = SW2Q_OFF + (size_t)D_MODEL * F_DIM * 2;
    const size_t EW2Q_OFF = EW1Q_OFF + (size_t)NE * F_DIM * D_MODEL * 2;
    const size_t H1_OFF   = EW2Q_OFF + (size_t)NE * D_MODEL * F_DIM * 2;
    const size_t PERM_OFF = H1_OFF + (size_t)(NTOK + 128) * F_DIM * 2;
    const size_t PROBG_OFF = PERM_OFF + (NTOK + 128) * 4;
    const size_t IDX_OFF   = PROBG_OFF + NTOK * 4;
    const size_t PROB_OFF  = IDX_OFF + NTOK * 4;
    const size_t BH_OFF    = PROB_OFF + NTOK * 4;
    const size_t BASE_OFF  = BH_OFF + HBLK * NE * 4;
    const size_t TILE_OFF  = BASE_OFF + HBLK * NE * 4;

    unsigned short* h     = (unsigned short*)(ws + H_OFF);
    unsigned short* sw1q  = (unsigned short*)(ws + SW1Q_OFF);
    unsigned short* sw2q  = (unsigned short*)(ws + SW2Q_OFF);
    unsigned short* ew1q  = (unsigned short*)(ws + EW1Q_OFF);
    unsigned short* ew2q  = (unsigned short*)(ws + EW2Q_OFF);
    unsigned short* h1    = (unsigned short*)(ws + H1_OFF);
    int*   tok_perm = (int*)(ws + PERM_OFF);
    float* probg    = (float*)(ws + PROBG_OFF);
    int*   idx      = (int*)(ws + IDX_OFF);
    float* prob     = (float*)(ws + PROB_OFF);
    int*   blockhist = (int*)(ws + BH_OFF);
    int*   base      = (int*)(ws + BASE_OFF);
    int4*  tilemap   = (int4*)(ws + TILE_OFF);

    quant_rows<1024><<<2048, 256, 0, stream>>>(sw1, sw1q);    // [2048,1024]
    quant_rows<2048><<<1024, 256, 0, stream>>>(sw2, sw2q);    // [1024,2048]
    quant_rows<1024><<<16384, 256, 0, stream>>>(ew1, ew1q);   // [8*2048,1024]
    quant_rows<2048><<<8192, 256, 0, stream>>>(ew2, ew2q);    // [8*1024,2048]

    ln_router<<<NTOK / 4, 256, 0, stream>>>(x, gam, bet, rw, h, idx, prob);

    // routing plan (no cross-XCD atomic contention anywhere)
    hist_kernel<<<HBLK, 256, 0, stream>>>(idx, blockhist);
    scan_plan<<<1, 64, 0, stream>>>(blockhist, base, tilemap, tok_perm);
    scatter_tokens<<<HBLK, 256, 0, stream>>>(idx, prob, base, tok_perm, probg);

    // shared expert: h1 = silu(h @ sw1^T); out = h1 @ sw2^T
    gemm_nt<0><<<dim3(F_DIM / 128, NTOK / 128), 256, 0, stream>>>(
        h, sw1q, h1, F_DIM, D_MODEL, nullptr, 0, nullptr, nullptr);
    gemm_nt<1><<<dim3(D_MODEL / 128, NTOK / 128), 256, 0, stream>>>(
        h1, sw2q, out, D_MODEL, F_DIM, nullptr, 0, nullptr, nullptr);

    // routed experts: h1g = silu(h[perm] @ ew1[e]^T); out[tok] += p * (h1g @ ew2[e]^T)
    gemm_nt<2><<<dim3(F_DIM / 128, MAXT), 256, 0, stream>>>(
        h, ew1q, h1, F_DIM, D_MODEL, tilemap, (long long)F_DIM * D_MODEL, tok_perm, nullptr);
    gemm_nt<3><<<dim3(D_MODEL / 128, MAXT), 256, 0, stream>>>(
        h1, ew2q, out, D_MODEL, F_DIM, tilemap, (long long)D_MODEL * F_DIM, tok_perm, probg);
}

// Round 4
// 493.751 us; speedup vs baseline: 1.3360x; 1.3360x over previous
//
#include <hip/hip_runtime.h>
#include <hip/hip_bf16.h>

#define D_MODEL 1024
#define F_DIM   2048
#define NE      8
#define NTOK    8192
#define MAXT    72
#define HBLK    32          // histogram/scatter blocks (256 tokens each)

typedef __attribute__((ext_vector_type(8))) short bf16x8;
typedef __attribute__((ext_vector_type(4))) float f32x4;

__device__ __forceinline__ unsigned short f2b(float f) {
    unsigned int u = __float_as_uint(f);
    u += 0x7FFFu + ((u >> 16) & 1u);          // RNE
    return (unsigned short)(u >> 16);
}
__device__ __forceinline__ unsigned int pack2(float a, float b) {
    return (unsigned int)f2b(a) | ((unsigned int)f2b(b) << 16);
}
__device__ __forceinline__ void async16(const void* g, void* l) {
    __builtin_amdgcn_global_load_lds((const __attribute__((address_space(1))) void*)g,
                                     (__attribute__((address_space(3))) void*)l, 16, 0, 0);
}

// ------------- ternary quantization: fp32 rows -> bf16 {-s,0,+s} ----------------
template <int K>
__global__ __launch_bounds__(256) void quant_rows(const float* __restrict__ W,
                                                  unsigned short* __restrict__ Q) {
    constexpr int PER = K / 256;
    constexpr int PV  = PER / 4;
    __shared__ float sred[4];
    const int tid = threadIdx.x;
    const size_t row = blockIdx.x;
    const float4* Wv = (const float4*)(W + row * (size_t)K) + tid * PV;
    float4 v[PV];
#pragma unroll
    for (int i = 0; i < PV; i++) v[i] = Wv[i];
    float s = 0.f;
#pragma unroll
    for (int i = 0; i < PV; i++)
        s += fabsf(v[i].x) + fabsf(v[i].y) + fabsf(v[i].z) + fabsf(v[i].w);
#pragma unroll
    for (int o = 32; o > 0; o >>= 1) s += __shfl_down(s, o);
    if ((tid & 63) == 0) sred[tid >> 6] = s;
    __syncthreads();
    float scale = (sred[0] + sred[1] + sred[2] + sred[3]) * (1.0f / K);
    scale = fmaxf(scale, 1e-5f);
    const float inv = 1.0f / scale;
    unsigned int* Qu = (unsigned int*)(Q + row * (size_t)K) + tid * (PER / 2);
#pragma unroll
    for (int i = 0; i < PV; i++) {
        float q0 = fminf(1.f, fmaxf(-1.f, rintf(v[i].x * inv))) * scale;
        float q1 = fminf(1.f, fmaxf(-1.f, rintf(v[i].y * inv))) * scale;
        float q2 = fminf(1.f, fmaxf(-1.f, rintf(v[i].z * inv))) * scale;
        float q3 = fminf(1.f, fmaxf(-1.f, rintf(v[i].w * inv))) * scale;
        Qu[2 * i]     = pack2(q0, q1);
        Qu[2 * i + 1] = pack2(q2, q3);
    }
}

// -------- fused LayerNorm + router: ONE WAVE PER TOKEN, no atomics --------------
__global__ __launch_bounds__(256) void ln_router(const float* __restrict__ x,
                                                 const float* __restrict__ gamma,
                                                 const float* __restrict__ beta,
                                                 const float* __restrict__ rw,
                                                 unsigned short* __restrict__ h,
                                                 int* __restrict__ top_idx,
                                                 float* __restrict__ top_prob) {
    const int lane = threadIdx.x & 63;
    const size_t tok = blockIdx.x * 4 + (threadIdx.x >> 6);

    const float4* xr = (const float4*)(x + tok * D_MODEL);
    float4 xv[4];
#pragma unroll
    for (int i = 0; i < 4; i++) xv[i] = xr[lane + 64 * i];
    float s = 0.f, q = 0.f;
#pragma unroll
    for (int i = 0; i < 4; i++) {
        s += xv[i].x + xv[i].y + xv[i].z + xv[i].w;
        q += xv[i].x * xv[i].x + xv[i].y * xv[i].y + xv[i].z * xv[i].z + xv[i].w * xv[i].w;
    }
#pragma unroll
    for (int o = 32; o > 0; o >>= 1) { s += __shfl_down(s, o); q += __shfl_down(q, o); }
    s = __shfl(s, 0); q = __shfl(q, 0);
    const float mean = s * (1.0f / D_MODEL);
    const float rstd = rsqrtf(q * (1.0f / D_MODEL) - mean * mean + 1e-5f);

    float4 hv[4];
    unsigned int* hr = (unsigned int*)(h + tok * D_MODEL);
#pragma unroll
    for (int i = 0; i < 4; i++) {
        const float4 g  = ((const float4*)gamma)[lane + 64 * i];
        const float4 bt = ((const float4*)beta)[lane + 64 * i];
        hv[i].x = (xv[i].x - mean) * rstd * g.x + bt.x;
        hv[i].y = (xv[i].y - mean) * rstd * g.y + bt.y;
        hv[i].z = (xv[i].z - mean) * rstd * g.z + bt.z;
        hv[i].w = (xv[i].w - mean) * rstd * g.w + bt.w;
        hr[2 * (lane + 64 * i)]     = pack2(hv[i].x, hv[i].y);
        hr[2 * (lane + 64 * i) + 1] = pack2(hv[i].z, hv[i].w);
    }

    float acc[NE];
#pragma unroll
    for (int e = 0; e < NE; e++) {
        const float4* rr = (const float4*)(rw + e * D_MODEL);
        float a = 0.f;
#pragma unroll
        for (int i = 0; i < 4; i++) {
            const float4 r = rr[lane + 64 * i];
            a += hv[i].x * r.x + hv[i].y * r.y + hv[i].z * r.z + hv[i].w * r.w;
        }
        acc[e] = a;
    }
#pragma unroll
    for (int e = 0; e < NE; e++) {
#pragma unroll
        for (int o = 32; o > 0; o >>= 1) acc[e] += __shfl_down(acc[e], o);
    }
    if (lane == 0) {
        float m = acc[0]; int bi = 0;
#pragma unroll
        for (int e = 1; e < NE; e++) { if (acc[e] > m) { m = acc[e]; bi = e; } }
        float se = 0.f;
#pragma unroll
        for (int e = 0; e < NE; e++) se += __expf(acc[e] - m);
        top_idx[tok]  = bi;
        top_prob[tok] = 1.0f / se;
    }
}

// ------- routing plan: per-block LDS histogram -> parallel scan -> scatter -------
__global__ __launch_bounds__(256) void hist_kernel(const int* __restrict__ top_idx,
                                                   int* __restrict__ blockhist) {
    __shared__ int lh[NE];
    if (threadIdx.x < NE) lh[threadIdx.x] = 0;
    __syncthreads();
    const int t = blockIdx.x * 256 + threadIdx.x;
    atomicAdd(&lh[top_idx[t]], 1);
    __syncthreads();
    if (threadIdx.x < NE) blockhist[blockIdx.x * NE + threadIdx.x] = lh[threadIdx.x];
}

// one 256-thread block; all global traffic is parallel (round-3 serial version was 157us)
__global__ __launch_bounds__(256) void scan_plan(const int* __restrict__ blockhist,
                                                 int* __restrict__ base,
                                                 int4* __restrict__ tilemap,
                                                 int* __restrict__ tok_perm) {
    __shared__ int sh[HBLK * NE];
    __shared__ int counts[NE];
    __shared__ int offsets[NE];
    __shared__ int tstart[NE + 1];
    const int tid = threadIdx.x;
    sh[tid] = blockhist[tid];
    __syncthreads();
    if (tid < NE) {
        int c = 0;
#pragma unroll
        for (int b = 0; b < HBLK; b++) c += sh[b * NE + tid];
        counts[tid] = c;
    }
    __syncthreads();
    if (tid == 0) {
        int off = 0, slot = 0;
#pragma unroll
        for (int e = 0; e < NE; e++) {
            offsets[e] = off;
            tstart[e] = slot;
            slot += (counts[e] + 127) >> 7;
            off += counts[e];
        }
        tstart[NE] = slot;
    }
    __syncthreads();
    if (tid < MAXT) {
        int4 t; t.x = 0; t.y = 0; t.z = 0; t.w = 0;
#pragma unroll
        for (int e = 0; e < NE; e++) {
            if (tid >= tstart[e] && tid < tstart[e + 1]) {
                const int k = (tid - tstart[e]) << 7;
                t.x = e; t.y = offsets[e] + k; t.z = min(128, counts[e] - k);
            }
        }
        tilemap[tid] = t;
    }
    {
        const int b = tid >> 3, e = tid & 7;
        int r = offsets[e];
        for (int bb = 0; bb < b; bb++) r += sh[bb * NE + e];
        base[b * NE + e] = r;
    }
    if (tid < 128) tok_perm[NTOK + tid] = 0;   // pad rows read by gather-tile A loads
}

__global__ __launch_bounds__(256) void scatter_tokens(const int* __restrict__ top_idx,
                                                      const float* __restrict__ top_prob,
                                                      const int* __restrict__ base,
                                                      int* __restrict__ tok_perm,
                                                      float* __restrict__ probg) {
    __shared__ int cur[NE];
    if (threadIdx.x < NE) cur[threadIdx.x] = base[blockIdx.x * NE + threadIdx.x];
    __syncthreads();
    const int t = blockIdx.x * 256 + threadIdx.x;
    const int e = top_idx[t];
    const int pos = atomicAdd(&cur[e], 1);     // LDS atomic — block-local, cheap
    tok_perm[pos] = t;
    probg[pos] = top_prob[t];
}

// ---------------- m97-style bf16 NT GEMM: C[M,N] = A[M,K] * B[N,K]^T ------------
// A,B bf16; EPI: 0 silu->bf16 (shared G1), 1 fp32 store (shared G2),
//              2 tiled + A-gather via tok_perm, silu->bf16 (routed G1),
//              3 tiled scatter-add fp32 out[tok] += p*v (routed G2)
template <int EPI>
__global__ __launch_bounds__(256) void gemm_nt(const unsigned short* __restrict__ A,
                                               const unsigned short* __restrict__ Bw,
                                               void* __restrict__ Cv,
                                               int N, int K,
                                               const int4* __restrict__ tilemap,
                                               long long bstride,
                                               const int* __restrict__ tok_perm,
                                               const float* __restrict__ probg) {
    int m0, rowsValid;
    const unsigned short* B = Bw;
    if (EPI >= 2) {
        int4 tm = tilemap[blockIdx.y];
        rowsValid = tm.z;
        if (rowsValid == 0) return;
        m0 = tm.y;
        B += (size_t)tm.x * (size_t)bstride;
    } else {
        m0 = blockIdx.y * 128;
        rowsValid = 128;
    }
    const int n0 = blockIdx.x * 128;

    __shared__ unsigned short As[128 * 32];
    __shared__ unsigned short Bs[128 * 32];

    const int tid = threadIdx.x;
    const int lane = tid & 63;
    const int w = tid >> 6;
    const int wm = w >> 1, wn = w & 1;

    f32x4 acc[4][4];
#pragma unroll
    for (int i = 0; i < 4; i++)
#pragma unroll
        for (int j = 0; j < 4; j++) acc[i][j] = (f32x4){0.f, 0.f, 0.f, 0.f};

    const int rS = w * 16 + (lane >> 2);
    const int cS = (lane & 3) * 8;
    size_t ar0, ar1;
    if (EPI == 2) {                       // A-row gather through token permutation
        ar0 = (size_t)tok_perm[m0 + rS] * (size_t)K;
        ar1 = (size_t)tok_perm[m0 + rS + 64] * (size_t)K;
    } else {
        ar0 = (size_t)(m0 + rS) * (size_t)K;
        ar1 = (size_t)(m0 + rS + 64) * (size_t)K;
    }
    const unsigned short* a0 = A + ar0 + cS;
    const unsigned short* a1 = A + ar1 + cS;
    const unsigned short* b0 = B + (size_t)(n0 + rS) * K + cS;
    const unsigned short* b1 = B + (size_t)(n0 + rS + 64) * K + cS;
    unsigned short* asl = As + w * 512;
    unsigned short* bsl = Bs + w * 512;

    const int fr = lane & 15, fq = lane >> 4;
    const bf16x8* Ar = (const bf16x8*)As;
    const bf16x8* Br = (const bf16x8*)Bs;
    const int aBase = (wm * 64 + fr) * 4 + fq;
    const int bBase = (wn * 64 + fr) * 4 + fq;

    for (int k0 = 0; k0 < K; k0 += 32) {
        async16(a0 + k0, asl);
        async16(a1 + k0, asl + 2048);
        async16(b0 + k0, bsl);
        async16(b1 + k0, bsl + 2048);
        __syncthreads();
        bf16x8 af[4], bfr[4];
#pragma unroll
        for (int i = 0; i < 4; i++) af[i] = Ar[aBase + i * 64];
#pragma unroll
        for (int j = 0; j < 4; j++) bfr[j] = Br[bBase + j * 64];
#pragma unroll
        for (int i = 0; i < 4; i++)
#pragma unroll
            for (int j = 0; j < 4; j++)
                acc[i][j] = __builtin_amdgcn_mfma_f32_16x16x32_bf16(af[i], bfr[j], acc[i][j], 0, 0, 0);
        __syncthreads();
    }

    // epilogue: C/D layout col=lane&15, row=quad*4+reg (m89-verified)
#pragma unroll
    for (int i = 0; i < 4; i++) {
        const int rb = wm * 64 + i * 16 + fq * 4;
#pragma unroll
        for (int t = 0; t < 4; t++) {
            const int r = rb + t;
            if (r < rowsValid) {
#pragma unroll
                for (int j = 0; j < 4; j++) {
                    const int c = n0 + wn * 64 + j * 16 + fr;
                    float v = acc[i][j][t];
                    if (EPI == 0 || EPI == 2) {
                        v = v / (1.0f + __expf(-v));
                        ((unsigned short*)Cv)[(size_t)(m0 + r) * N + c] = f2b(v);
                    } else if (EPI == 1) {
                        ((float*)Cv)[(size_t)(m0 + r) * N + c] = v;
                    } else {
                        const int tokr = tok_perm[m0 + r];
                        const float p = probg[m0 + r];
                        float* crow = (float*)Cv + (size_t)tokr * N;
                        crow[c] = crow[c] + p * v;
                    }
                }
            }
        }
    }
}

// ---------------- launch ---------------------------------------------------------
extern "C" void kernel_launch(void* const* d_in, const int* in_sizes, int n_in,
                              void* d_out, int out_size, void* d_ws, size_t ws_size,
                              hipStream_t stream) {
    const float* x   = (const float*)d_in[0];
    const float* sw1 = (const float*)d_in[1];
    const float* sw2 = (const float*)d_in[2];
    const float* ew1 = (const float*)d_in[3];
    const float* ew2 = (const float*)d_in[4];
    const float* rw  = (const float*)d_in[5];
    const float* gam = (const float*)d_in[6];
    const float* bet = (const float*)d_in[7];
    float* out = (float*)d_out;

    char* ws = (char*)d_ws;
    const size_t H_OFF    = 0;
    const size_t SW1Q_OFF = H_OFF + (size_t)NTOK * D_MODEL * 2;
    const size_t SW2Q_OFF = SW1Q_OFF + (size_t)F_DIM * D_MODEL * 2;
    const size_t EW1Q_OFF = SW2Q_OFF + (size_t)D_MODEL * F_DIM * 2;
    const size_t EW2Q_OFF = EW1Q_OFF + (size_t)NE * F_DIM * D_MODEL * 2;
    const size_t H1_OFF   = EW2Q_OFF + (size_t)NE * D_MODEL * F_DIM * 2;
    const size_t PERM_OFF = H1_OFF + (size_t)(NTOK + 128) * F_DIM * 2;
    const size_t PROBG_OFF = PERM_OFF + (NTOK + 128) * 4;
    const size_t IDX_OFF   = PROBG_OFF + NTOK * 4;
    const size_t PROB_OFF  = IDX_OFF + NTOK * 4;
    const size_t BH_OFF    = PROB_OFF + NTOK * 4;
    const size_t BASE_OFF  = BH_OFF + HBLK * NE * 4;
    const size_t TILE_OFF  = BASE_OFF + HBLK * NE * 4;

    unsigned short* h     = (unsigned short*)(ws + H_OFF);
    unsigned short* sw1q  = (unsigned short*)(ws + SW1Q_OFF);
    unsigned short* sw2q  = (unsigned short*)(ws + SW2Q_OFF);
    unsigned short* ew1q  = (unsigned short*)(ws + EW1Q_OFF);
    unsigned short* ew2q  = (unsigned short*)(ws + EW2Q_OFF);
    unsigned short* h1    = (unsigned short*)(ws + H1_OFF);
    int*   tok_perm = (int*)(ws + PERM_OFF);
    float* probg    = (float*)(ws + PROBG_OFF);
    int*   idx      = (int*)(ws + IDX_OFF);
    float* prob     = (float*)(ws + PROB_OFF);
    int*   blockhist = (int*)(ws + BH_OFF);
    int*   base      = (int*)(ws + BASE_OFF);
    int4*  tilemap   = (int4*)(ws + TILE_OFF);

    quant_rows<1024><<<2048, 256, 0, stream>>>(sw1, sw1q);    // [2048,1024]
    quant_rows<2048><<<1024, 256, 0, stream>>>(sw2, sw2q);    // [1024,2048]
    quant_rows<1024><<<16384, 256, 0, stream>>>(ew1, ew1q);   // [8*2048,1024]
    quant_rows<2048><<<8192, 256, 0, stream>>>(ew2, ew2q);    // [8*1024,2048]

    ln_router<<<NTOK / 4, 256, 0, stream>>>(x, gam, bet, rw, h, idx, prob);

    // routing plan (no cross-XCD atomic contention, no serial global access)
    hist_kernel<<<HBLK, 256, 0, stream>>>(idx, blockhist);
    scan_plan<<<1, 256, 0, stream>>>(blockhist, base, tilemap, tok_perm);
    scatter_tokens<<<HBLK, 256, 0, stream>>>(idx, prob, base, tok_perm, probg);

    // shared expert: h1 = silu(h @ sw1^T); out = h1 @ sw2^T
    gemm_nt<0><<<dim3(F_DIM / 128, NTOK / 128), 256, 0, stream>>>(
        h, sw1q, h1, F_DIM, D_MODEL, nullptr, 0, nullptr, nullptr);
    gemm_nt<1><<<dim3(D_MODEL / 128, NTOK / 128), 256, 0, stream>>>(
        h1, sw2q, out, D_MODEL, F_DIM, nullptr, 0, nullptr, nullptr);

    // routed experts: h1g = silu(h[perm] @ ew1[e]^T); out[tok] += p * (h1g @ ew2[e]^T)
    gemm_nt<2><<<dim3(F_DIM / 128, MAXT), 256, 0, stream>>>(
        h, ew1q, h1, F_DIM, D_MODEL, tilemap, (long long)F_DIM * D_MODEL, tok_perm, nullptr);
    gemm_nt<3><<<dim3(D_MODEL / 128, MAXT), 256, 0, stream>>>(
        h1, ew2q, out, D_MODEL, F_DIM, tilemap, (long long)D_MODEL * F_DIM, tok_perm, probg);
}

// Round 5
// 446.877 us; speedup vs baseline: 1.4761x; 1.1049x over previous
//
#include <hip/hip_runtime.h>
#include <hip/hip_bf16.h>

#define D_MODEL 1024
#define F_DIM   2048
#define NE      8
#define NTOK    8192
#define MAXT    72
#define HBLK    32          // histogram/scatter blocks (256 tokens each)

typedef __attribute__((ext_vector_type(8))) short bf16x8;
typedef __attribute__((ext_vector_type(4))) float f32x4;

__device__ __forceinline__ unsigned short f2b(float f) {
    unsigned int u = __float_as_uint(f);
    u += 0x7FFFu + ((u >> 16) & 1u);          // RNE
    return (unsigned short)(u >> 16);
}
__device__ __forceinline__ unsigned int pack2(float a, float b) {
    return (unsigned int)f2b(a) | ((unsigned int)f2b(b) << 16);
}
__device__ __forceinline__ void async16(const void* g, void* l) {
    __builtin_amdgcn_global_load_lds((const __attribute__((address_space(1))) void*)g,
                                     (__attribute__((address_space(3))) void*)l, 16, 0, 0);
}

// ------------- ternary quantization: fp32 rows -> bf16 {-s,0,+s} ----------------
template <int K>
__global__ __launch_bounds__(256) void quant_rows(const float* __restrict__ W,
                                                  unsigned short* __restrict__ Q) {
    constexpr int PER = K / 256;
    constexpr int PV  = PER / 4;
    __shared__ float sred[4];
    const int tid = threadIdx.x;
    const size_t row = blockIdx.x;
    const float4* Wv = (const float4*)(W + row * (size_t)K) + tid * PV;
    float4 v[PV];
#pragma unroll
    for (int i = 0; i < PV; i++) v[i] = Wv[i];
    float s = 0.f;
#pragma unroll
    for (int i = 0; i < PV; i++)
        s += fabsf(v[i].x) + fabsf(v[i].y) + fabsf(v[i].z) + fabsf(v[i].w);
#pragma unroll
    for (int o = 32; o > 0; o >>= 1) s += __shfl_down(s, o);
    if ((tid & 63) == 0) sred[tid >> 6] = s;
    __syncthreads();
    float scale = (sred[0] + sred[1] + sred[2] + sred[3]) * (1.0f / K);
    scale = fmaxf(scale, 1e-5f);
    const float inv = 1.0f / scale;
    unsigned int* Qu = (unsigned int*)(Q + row * (size_t)K) + tid * (PER / 2);
#pragma unroll
    for (int i = 0; i < PV; i++) {
        float q0 = fminf(1.f, fmaxf(-1.f, rintf(v[i].x * inv))) * scale;
        float q1 = fminf(1.f, fmaxf(-1.f, rintf(v[i].y * inv))) * scale;
        float q2 = fminf(1.f, fmaxf(-1.f, rintf(v[i].z * inv))) * scale;
        float q3 = fminf(1.f, fmaxf(-1.f, rintf(v[i].w * inv))) * scale;
        Qu[2 * i]     = pack2(q0, q1);
        Qu[2 * i + 1] = pack2(q2, q3);
    }
}

// -------- fused LayerNorm + router: one wave per token, no atomics --------------
__global__ __launch_bounds__(256) void ln_router(const float* __restrict__ x,
                                                 const float* __restrict__ gamma,
                                                 const float* __restrict__ beta,
                                                 const float* __restrict__ rw,
                                                 unsigned short* __restrict__ h,
                                                 int* __restrict__ top_idx,
                                                 float* __restrict__ top_prob) {
    const int lane = threadIdx.x & 63;
    const size_t tok = blockIdx.x * 4 + (threadIdx.x >> 6);

    const float4* xr = (const float4*)(x + tok * D_MODEL);
    float4 xv[4];
#pragma unroll
    for (int i = 0; i < 4; i++) xv[i] = xr[lane + 64 * i];
    float s = 0.f, q = 0.f;
#pragma unroll
    for (int i = 0; i < 4; i++) {
        s += xv[i].x + xv[i].y + xv[i].z + xv[i].w;
        q += xv[i].x * xv[i].x + xv[i].y * xv[i].y + xv[i].z * xv[i].z + xv[i].w * xv[i].w;
    }
#pragma unroll
    for (int o = 32; o > 0; o >>= 1) { s += __shfl_down(s, o); q += __shfl_down(q, o); }
    s = __shfl(s, 0); q = __shfl(q, 0);
    const float mean = s * (1.0f / D_MODEL);
    const float rstd = rsqrtf(q * (1.0f / D_MODEL) - mean * mean + 1e-5f);

    float4 hv[4];
    unsigned int* hr = (unsigned int*)(h + tok * D_MODEL);
#pragma unroll
    for (int i = 0; i < 4; i++) {
        const float4 g  = ((const float4*)gamma)[lane + 64 * i];
        const float4 bt = ((const float4*)beta)[lane + 64 * i];
        hv[i].x = (xv[i].x - mean) * rstd * g.x + bt.x;
        hv[i].y = (xv[i].y - mean) * rstd * g.y + bt.y;
        hv[i].z = (xv[i].z - mean) * rstd * g.z + bt.z;
        hv[i].w = (xv[i].w - mean) * rstd * g.w + bt.w;
        hr[2 * (lane + 64 * i)]     = pack2(hv[i].x, hv[i].y);
        hr[2 * (lane + 64 * i) + 1] = pack2(hv[i].z, hv[i].w);
    }

    float acc[NE];
#pragma unroll
    for (int e = 0; e < NE; e++) {
        const float4* rr = (const float4*)(rw + e * D_MODEL);
        float a = 0.f;
#pragma unroll
        for (int i = 0; i < 4; i++) {
            const float4 r = rr[lane + 64 * i];
            a += hv[i].x * r.x + hv[i].y * r.y + hv[i].z * r.z + hv[i].w * r.w;
        }
        acc[e] = a;
    }
#pragma unroll
    for (int e = 0; e < NE; e++) {
#pragma unroll
        for (int o = 32; o > 0; o >>= 1) acc[e] += __shfl_down(acc[e], o);
    }
    if (lane == 0) {
        float m = acc[0]; int bi = 0;
#pragma unroll
        for (int e = 1; e < NE; e++) { if (acc[e] > m) { m = acc[e]; bi = e; } }
        float se = 0.f;
#pragma unroll
        for (int e = 0; e < NE; e++) se += __expf(acc[e] - m);
        top_idx[tok]  = bi;
        top_prob[tok] = 1.0f / se;
    }
}

// ------- routing plan: per-block LDS histogram -> parallel scan -> scatter -------
__global__ __launch_bounds__(256) void hist_kernel(const int* __restrict__ top_idx,
                                                   int* __restrict__ blockhist) {
    __shared__ int lh[NE];
    if (threadIdx.x < NE) lh[threadIdx.x] = 0;
    __syncthreads();
    const int t = blockIdx.x * 256 + threadIdx.x;
    atomicAdd(&lh[top_idx[t]], 1);
    __syncthreads();
    if (threadIdx.x < NE) blockhist[blockIdx.x * NE + threadIdx.x] = lh[threadIdx.x];
}

// one 256-thread block; all global traffic parallel
__global__ __launch_bounds__(256) void scan_plan(const int* __restrict__ blockhist,
                                                 int* __restrict__ base,
                                                 int4* __restrict__ tilemap,
                                                 int* __restrict__ tok_perm) {
    __shared__ int sh[HBLK * NE];
    __shared__ int counts[NE];
    __shared__ int offsets[NE];
    __shared__ int tstart[NE + 1];
    const int tid = threadIdx.x;
    sh[tid] = blockhist[tid];
    __syncthreads();
    if (tid < NE) {
        int c = 0;
#pragma unroll
        for (int b = 0; b < HBLK; b++) c += sh[b * NE + tid];
        counts[tid] = c;
    }
    __syncthreads();
    if (tid == 0) {
        int off = 0, slot = 0;
#pragma unroll
        for (int e = 0; e < NE; e++) {
            offsets[e] = off;
            tstart[e] = slot;
            slot += (counts[e] + 127) >> 7;
            off += counts[e];
        }
        tstart[NE] = slot;
    }
    __syncthreads();
    if (tid < MAXT) {
        int4 t; t.x = 0; t.y = 0; t.z = 0; t.w = 0;
#pragma unroll
        for (int e = 0; e < NE; e++) {
            if (tid >= tstart[e] && tid < tstart[e + 1]) {
                const int k = (tid - tstart[e]) << 7;
                t.x = e; t.y = offsets[e] + k; t.z = min(128, counts[e] - k);
            }
        }
        tilemap[tid] = t;
    }
    {
        const int b = tid >> 3, e = tid & 7;
        int r = offsets[e];
        for (int bb = 0; bb < b; bb++) r += sh[bb * NE + e];
        base[b * NE + e] = r;
    }
    if (tid < 128) tok_perm[NTOK + tid] = 0;   // pad rows for gather-tile A loads
}

__global__ __launch_bounds__(256) void scatter_tokens(const int* __restrict__ top_idx,
                                                      const float* __restrict__ top_prob,
                                                      const int* __restrict__ base,
                                                      int* __restrict__ tok_perm,
                                                      float* __restrict__ probg) {
    __shared__ int cur[NE];
    if (threadIdx.x < NE) cur[threadIdx.x] = base[blockIdx.x * NE + threadIdx.x];
    __syncthreads();
    const int t = blockIdx.x * 256 + threadIdx.x;
    const int e = top_idx[t];
    const int pos = atomicAdd(&cur[e], 1);     // LDS atomic — block-local
    tok_perm[pos] = t;
    probg[pos] = top_prob[t];
}

// ------------- BK=64, XOR-swizzled LDS, bf16 NT GEMM: C = A * B^T ----------------
// LDS tile [128 rows][64 cols]; physical 16B-chunk p of row r holds global chunk p^(r&7).
// MODE 0: merged G1 — blockIdx.y<64: shared (A=h direct, B=sw1q, C=h1s, silu->bf16)
//                     else: routed slot (A=h gathered via tok_perm, B=ew1q[e], C=h1r, silu->bf16)
// MODE 1: routed G2 — A=h1r, B=ew2q[e], Out[tok_perm[row]] = p * v   (plain fp32 store)
// MODE 2: shared G2 — A=h1s, B=sw2q,    Out[row] += v                (read-add fp32)
template <int MODE>
__global__ __launch_bounds__(256) void gemm64(const unsigned short* __restrict__ A,
                                              const unsigned short* __restrict__ Bmain,
                                              const unsigned short* __restrict__ Bexp,
                                              unsigned short* __restrict__ C1s,
                                              unsigned short* __restrict__ C1r,
                                              float* __restrict__ Out,
                                              int N, int K,
                                              const int4* __restrict__ tilemap,
                                              const int* __restrict__ tok_perm,
                                              const float* __restrict__ probg) {
    int m0, rowsValid;
    const unsigned short* B;
    unsigned short* Cb = nullptr;
    bool gather = false;
    if (MODE == 0) {
        if (blockIdx.y < 64) {
            m0 = blockIdx.y * 128; rowsValid = 128; B = Bmain; Cb = C1s;
        } else {
            int4 tm = tilemap[blockIdx.y - 64];
            if (tm.z == 0) return;
            m0 = tm.y; rowsValid = tm.z;
            B = Bexp + (size_t)tm.x * F_DIM * D_MODEL;
            Cb = C1r; gather = true;
        }
    } else if (MODE == 1) {
        int4 tm = tilemap[blockIdx.y];
        if (tm.z == 0) return;
        m0 = tm.y; rowsValid = tm.z;
        B = Bmain + (size_t)tm.x * D_MODEL * F_DIM;
    } else {
        m0 = blockIdx.y * 128; rowsValid = 128; B = Bmain;
    }
    const int n0 = blockIdx.x * 128;

    __shared__ unsigned short As[128 * 64];   // 16 KB
    __shared__ unsigned short Bs[128 * 64];   // 16 KB

    const int tid = threadIdx.x;
    const int lane = tid & 63;
    const int w = tid >> 6;
    const int wm = w >> 1, wn = w & 1;

    f32x4 acc[4][4];
#pragma unroll
    for (int i = 0; i < 4; i++)
#pragma unroll
        for (int j = 0; j < 4; j++) acc[i][j] = (f32x4){0.f, 0.f, 0.f, 0.f};

    // staging: wave w stages rows [w*32, w*32+32) in 4 calls of 8 rows each.
    // lane -> row w*32+q*8+(lane>>3), swizzled source col chunk ((lane&7)^(lane>>3))*8
    const int sRow = lane >> 3;
    const int sCol = ((lane & 7) ^ sRow) * 8;
    const unsigned short* aP[4];
    const unsigned short* bP[4];
#pragma unroll
    for (int qq = 0; qq < 4; qq++) {
        const int ra = w * 32 + qq * 8 + sRow;
        size_t arow;
        if (MODE == 0) arow = gather ? (size_t)tok_perm[m0 + ra] : (size_t)(m0 + ra);
        else           arow = (size_t)(m0 + ra);
        aP[qq] = A + arow * (size_t)K + sCol;
        bP[qq] = B + (size_t)(n0 + ra) * K + sCol;
    }
    unsigned short* aL = As + w * 2048;   // w*32 rows * 64 elems
    unsigned short* bL = Bs + w * 2048;

    const int fr = lane & 15, fq = lane >> 4;
    const bf16x8* Ar = (const bf16x8*)As;
    const bf16x8* Br = (const bf16x8*)Bs;

    for (int k0 = 0; k0 < K; k0 += 64) {
#pragma unroll
        for (int qq = 0; qq < 4; qq++) async16(aP[qq] + k0, aL + qq * 512);
#pragma unroll
        for (int qq = 0; qq < 4; qq++) async16(bP[qq] + k0, bL + qq * 512);
        __syncthreads();
#pragma unroll
        for (int kc = 0; kc < 2; kc++) {
            bf16x8 af[4], bf[4];
#pragma unroll
            for (int i = 0; i < 4; i++) {
                const int row = wm * 64 + i * 16 + fr;
                af[i] = Ar[row * 8 + (((kc << 2) + fq) ^ (fr & 7))];
            }
#pragma unroll
            for (int j = 0; j < 4; j++) {
                const int row = wn * 64 + j * 16 + fr;
                bf[j] = Br[row * 8 + (((kc << 2) + fq) ^ (fr & 7))];
            }
#pragma unroll
            for (int i = 0; i < 4; i++)
#pragma unroll
                for (int j = 0; j < 4; j++)
                    acc[i][j] = __builtin_amdgcn_mfma_f32_16x16x32_bf16(af[i], bf[j], acc[i][j], 0, 0, 0);
        }
        __syncthreads();
    }

    // epilogue: C/D layout col=lane&15, row=quad*4+reg (m89-verified)
#pragma unroll
    for (int i = 0; i < 4; i++) {
        const int rb = wm * 64 + i * 16 + fq * 4;
#pragma unroll
        for (int t = 0; t < 4; t++) {
            const int r = rb + t;
            if (r < rowsValid) {
#pragma unroll
                for (int j = 0; j < 4; j++) {
                    const int c = n0 + wn * 64 + j * 16 + fr;
                    float v = acc[i][j][t];
                    if (MODE == 0) {
                        v = v / (1.0f + __expf(-v));        // silu
                        Cb[(size_t)(m0 + r) * N + c] = f2b(v);
                    } else if (MODE == 1) {
                        const int tokr = tok_perm[m0 + r];
                        Out[(size_t)tokr * N + c] = probg[m0 + r] * v;
                    } else {
                        float* o = Out + (size_t)(m0 + r) * N + c;
                        *o = *o + v;
                    }
                }
            }
        }
    }
}

// ---------------- launch ---------------------------------------------------------
extern "C" void kernel_launch(void* const* d_in, const int* in_sizes, int n_in,
                              void* d_out, int out_size, void* d_ws, size_t ws_size,
                              hipStream_t stream) {
    const float* x   = (const float*)d_in[0];
    const float* sw1 = (const float*)d_in[1];
    const float* sw2 = (const float*)d_in[2];
    const float* ew1 = (const float*)d_in[3];
    const float* ew2 = (const float*)d_in[4];
    const float* rw  = (const float*)d_in[5];
    const float* gam = (const float*)d_in[6];
    const float* bet = (const float*)d_in[7];
    float* out = (float*)d_out;

    char* ws = (char*)d_ws;
    const size_t H_OFF    = 0;
    const size_t SW1Q_OFF = H_OFF + (size_t)NTOK * D_MODEL * 2;
    const size_t SW2Q_OFF = SW1Q_OFF + (size_t)F_DIM * D_MODEL * 2;
    const size_t EW1Q_OFF = SW2Q_OFF + (size_t)D_MODEL * F_DIM * 2;
    const size_t EW2Q_OFF = EW1Q_OFF + (size_t)NE * F_DIM * D_MODEL * 2;
    const size_t H1S_OFF  = EW2Q_OFF + (size_t)NE * D_MODEL * F_DIM * 2;
    const size_t H1R_OFF  = H1S_OFF + (size_t)NTOK * F_DIM * 2;
    const size_t PERM_OFF = H1R_OFF + (size_t)(NTOK + 128) * F_DIM * 2;
    const size_t PROBG_OFF = PERM_OFF + (NTOK + 128) * 4;
    const size_t IDX_OFF   = PROBG_OFF + NTOK * 4;
    const size_t PROB_OFF  = IDX_OFF + NTOK * 4;
    const size_t BH_OFF    = PROB_OFF + NTOK * 4;
    const size_t BASE_OFF  = BH_OFF + HBLK * NE * 4;
    const size_t TILE_OFF  = BASE_OFF + HBLK * NE * 4;

    unsigned short* h     = (unsigned short*)(ws + H_OFF);
    unsigned short* sw1q  = (unsigned short*)(ws + SW1Q_OFF);
    unsigned short* sw2q  = (unsigned short*)(ws + SW2Q_OFF);
    unsigned short* ew1q  = (unsigned short*)(ws + EW1Q_OFF);
    unsigned short* ew2q  = (unsigned short*)(ws + EW2Q_OFF);
    unsigned short* h1s   = (unsigned short*)(ws + H1S_OFF);
    unsigned short* h1r   = (unsigned short*)(ws + H1R_OFF);
    int*   tok_perm = (int*)(ws + PERM_OFF);
    float* probg    = (float*)(ws + PROBG_OFF);
    int*   idx      = (int*)(ws + IDX_OFF);
    float* prob     = (float*)(ws + PROB_OFF);
    int*   blockhist = (int*)(ws + BH_OFF);
    int*   base      = (int*)(ws + BASE_OFF);
    int4*  tilemap   = (int4*)(ws + TILE_OFF);

    quant_rows<1024><<<2048, 256, 0, stream>>>(sw1, sw1q);    // [2048,1024]
    quant_rows<2048><<<1024, 256, 0, stream>>>(sw2, sw2q);    // [1024,2048]
    quant_rows<1024><<<16384, 256, 0, stream>>>(ew1, ew1q);   // [8*2048,1024]
    quant_rows<2048><<<8192, 256, 0, stream>>>(ew2, ew2q);    // [8*1024,2048]

    ln_router<<<NTOK / 4, 256, 0, stream>>>(x, gam, bet, rw, h, idx, prob);

    hist_kernel<<<HBLK, 256, 0, stream>>>(idx, blockhist);
    scan_plan<<<1, 256, 0, stream>>>(blockhist, base, tilemap, tok_perm);
    scatter_tokens<<<HBLK, 256, 0, stream>>>(idx, prob, base, tok_perm, probg);

    // G1 merged: h1s = silu(h @ sw1^T)  [y<64] ; h1r = silu(h[perm] @ ew1[e]^T) [y>=64]
    gemm64<0><<<dim3(F_DIM / 128, 64 + MAXT), 256, 0, stream>>>(
        h, sw1q, ew1q, h1s, h1r, nullptr, F_DIM, D_MODEL, tilemap, tok_perm, nullptr);

    // G2 routed first (plain store covers every token row), then shared (read-add)
    gemm64<1><<<dim3(D_MODEL / 128, MAXT), 256, 0, stream>>>(
        h1r, ew2q, nullptr, nullptr, nullptr, out, D_MODEL, F_DIM, tilemap, tok_perm, probg);
    gemm64<2><<<dim3(D_MODEL / 128, NTOK / 128), 256, 0, stream>>>(
        h1s, sw2q, nullptr, nullptr, nullptr, out, D_MODEL, F_DIM, tilemap, tok_perm, probg);
}